// Round 7
// baseline (179.496 us; speedup 1.0000x reference)
//
#include <hip/hip_runtime.h>

#define B_SZ    64
#define S_LEN   448
#define D_MODEL 1024
#define N_HEAD  16
#define D_HEAD  64
#define NCH     28    // chunks per batch; 16 rows per block, 4 rows per wave

typedef float f4 __attribute__((ext_vector_type(4)));

// ws layout (float offsets)
#define PARTU_OFF  0                 // 1,835,008 floats: gemm partials (1.57M) then vstream partials [64][28][1024]
#define QBUF_OFF   1835008           // 65,536
#define KNBUF_OFF  1900544           // 65,536
#define VNBUF_OFF  1966080           // 65,536
#define SCORE_OFF  2031616           // 458,752  ([64][448][16], softmax in-place)
#define WV_OFF     2490368           // 65,536

// ---------------------------------------------------------------------------
// GEMM partial: P[(mat*8+kt)][b][n] = sum_{k in kt-range} X[b][k] * W[k][n]
// ---------------------------------------------------------------------------
__global__ __launch_bounds__(256) void gemm_part(
    const float* __restrict__ X,
    const float* __restrict__ W0, const float* __restrict__ W1,
    const float* __restrict__ W2,
    float* __restrict__ P)
{
    const int nt  = blockIdx.x;
    const int kt  = blockIdx.y;
    const int mat = blockIdx.z;
    const float* __restrict__ W = (mat == 0) ? W0 : ((mat == 1) ? W1 : W2);

    const int t  = threadIdx.x;
    const int n  = nt * 64 + (t & 63);
    const int b0 = __builtin_amdgcn_readfirstlane((t >> 6) * 16);
    const int k0 = kt * 128;

    float acc[16];
#pragma unroll
    for (int j = 0; j < 16; ++j) acc[j] = 0.f;

#pragma unroll 8
    for (int k = k0; k < k0 + 128; ++k) {
        const float w = W[k * D_MODEL + n];
#pragma unroll
        for (int j = 0; j < 16; ++j)
            acc[j] += X[(b0 + j) * D_MODEL + k] * w;
    }

    float* p = P + (size_t)(mat * 8 + kt) * (B_SZ * D_MODEL);
#pragma unroll
    for (int j = 0; j < 16; ++j)
        p[(b0 + j) * D_MODEL + n] = acc[j];
}

// materialize q(+bq), knew, vnew(+bv) from the k-split partials
__global__ __launch_bounds__(256) void prep(
    const float* __restrict__ P, const float* __restrict__ bq,
    const float* __restrict__ bv, float* __restrict__ qkv)
{
    const int i   = blockIdx.x * 256 + threadIdx.x;   // < 196608
    const int mat = i >> 16;
    const int r   = i & 65535;
    const int d   = r & (D_MODEL - 1);
    float s = (mat == 0) ? bq[d] : ((mat == 2) ? bv[d] : 0.f);
#pragma unroll
    for (int kt = 0; kt < 8; ++kt)
        s += P[(size_t)(mat * 8 + kt) * 65536 + r];
    qkv[i] = s;
}

// reduce 8 k-partials + bias -> final out projection
__global__ __launch_bounds__(256) void reduce_out(
    const float* __restrict__ P, const float* __restrict__ bo,
    float* __restrict__ out)
{
    const int i = blockIdx.x * 256 + threadIdx.x;     // < 65536
    float s = bo[i & (D_MODEL - 1)];
#pragma unroll
    for (int kt = 0; kt < 8; ++kt)
        s += P[(size_t)kt * 65536 + i];
    out[i] = s;
}

// ---------------------------------------------------------------------------
// K stream: pure copy kcache->kout (idx row from knbuf) + raw scores.
// grid = 1792 (= 64 b * 28 chunks), block 256. Wave w: 4 whole rows.
// Lane covers cols {j*256 + lane*4} for j=0..3; head(j,g)=j*4+(lane>>4).
// ---------------------------------------------------------------------------
__global__ __launch_bounds__(256) void kstream(
    const float* __restrict__ kcache, const float* __restrict__ qbuf,
    const float* __restrict__ knbuf, const float* __restrict__ amask,
    const int* __restrict__ idxp,
    float* __restrict__ kout, float* __restrict__ score)
{
    const int bid  = blockIdx.x;
    const int b    = bid / NCH;
    const int c    = bid % NCH;
    const int w    = threadIdx.x >> 6;
    const int lane = threadIdx.x & 63;
    const int g    = lane >> 4;
    const int idx  = idxp[0];
    const int s0   = c * 16 + w * 4;

    f4 q4[4];
#pragma unroll
    for (int j = 0; j < 4; ++j)
        q4[j] = *(const f4*)(qbuf + b * D_MODEL + j * 256 + lane * 4);

#pragma unroll
    for (int r = 0; r < 4; ++r) {
        const int s = s0 + r;                      // wave-uniform
        const size_t ro = ((size_t)b * S_LEN + s) * D_MODEL;
        float dot[4];
#pragma unroll
        for (int j = 0; j < 4; ++j) {
            f4 k4 = *(const f4*)(kcache + ro + j * 256 + lane * 4);
            if (s == idx)                          // uniform branch
                k4 = *(const f4*)(knbuf + b * D_MODEL + j * 256 + lane * 4);
            __builtin_nontemporal_store(k4, (f4*)(kout + ro + j * 256 + lane * 4));
            dot[j] = q4[j].x * k4.x + q4[j].y * k4.y + q4[j].z * k4.z + q4[j].w * k4.w;
        }
#pragma unroll
        for (int j = 0; j < 4; ++j) {
            float v = dot[j];
            v += __shfl_xor(v, 1);
            v += __shfl_xor(v, 2);
            v += __shfl_xor(v, 4);
            v += __shfl_xor(v, 8);
            if ((lane & 15) == 0)
                score[((size_t)b * S_LEN + s) * N_HEAD + (j * 4 + g)]
                    = v * 0.125f + amask[s];
        }
    }
}

// in-place softmax over s for each (b,h); one wave per (b,h)
__global__ __launch_bounds__(256) void softmax_k(float* __restrict__ sc)
{
    const int gw   = blockIdx.x * 4 + (threadIdx.x >> 6);  // 0..1023
    const int b    = gw >> 4;
    const int h    = gw & 15;
    const int lane = threadIdx.x & 63;

    float v[7];
    float mx = -1e30f;
#pragma unroll
    for (int t = 0; t < 7; ++t) {
        v[t] = sc[((size_t)b * S_LEN + lane + t * 64) * N_HEAD + h];
        mx = fmaxf(mx, v[t]);
    }
#pragma unroll
    for (int o = 1; o < 64; o <<= 1) mx = fmaxf(mx, __shfl_xor(mx, o));
    float sum = 0.f;
#pragma unroll
    for (int t = 0; t < 7; ++t) { v[t] = __expf(v[t] - mx); sum += v[t]; }
#pragma unroll
    for (int o = 1; o < 64; o <<= 1) sum += __shfl_xor(sum, o);
    const float inv = 1.f / sum;
#pragma unroll
    for (int t = 0; t < 7; ++t)
        sc[((size_t)b * S_LEN + lane + t * 64) * N_HEAD + h] = v[t] * inv;
}

// ---------------------------------------------------------------------------
// V stream: pure copy vcache->vout (idx row from vnbuf) + weighted partials.
// Same geometry as kstream; block LDS-reduces its 4 waves -> partial[b][c][d].
// ---------------------------------------------------------------------------
__global__ __launch_bounds__(256) void vstream(
    const float* __restrict__ vcache, const float* __restrict__ vnbuf,
    const float* __restrict__ wbuf, const int* __restrict__ idxp,
    float* __restrict__ vout, float* __restrict__ partial)
{
    const int bid  = blockIdx.x;
    const int b    = bid / NCH;
    const int c    = bid % NCH;
    const int w    = threadIdx.x >> 6;
    const int lane = threadIdx.x & 63;
    const int g    = lane >> 4;
    const int idx  = idxp[0];
    const int s0   = c * 16 + w * 4;

    f4 acc[4];
#pragma unroll
    for (int j = 0; j < 4; ++j) acc[j] = (f4)0.f;

#pragma unroll
    for (int r = 0; r < 4; ++r) {
        const int s = s0 + r;
        const size_t ro = ((size_t)b * S_LEN + s) * D_MODEL;
#pragma unroll
        for (int j = 0; j < 4; ++j) {
            const float wt = wbuf[((size_t)b * S_LEN + s) * N_HEAD + (j * 4 + g)];
            f4 v4 = *(const f4*)(vcache + ro + j * 256 + lane * 4);
            if (s == idx)
                v4 = *(const f4*)(vnbuf + b * D_MODEL + j * 256 + lane * 4);
            __builtin_nontemporal_store(v4, (f4*)(vout + ro + j * 256 + lane * 4));
            acc[j].x += wt * v4.x;
            acc[j].y += wt * v4.y;
            acc[j].z += wt * v4.z;
            acc[j].w += wt * v4.w;
        }
    }

    __shared__ float lds[4][D_MODEL];
#pragma unroll
    for (int j = 0; j < 4; ++j)
        *(f4*)&lds[w][j * 256 + lane * 4] = acc[j];
    __syncthreads();

    const int d = threadIdx.x * 4;   // 0..1023
    f4 s4 = *(const f4*)&lds[0][d];
    const f4 s1 = *(const f4*)&lds[1][d];
    const f4 s2 = *(const f4*)&lds[2][d];
    const f4 s3 = *(const f4*)&lds[3][d];
    s4.x += s1.x + s2.x + s3.x;
    s4.y += s1.y + s2.y + s3.y;
    s4.z += s1.z + s2.z + s3.z;
    s4.w += s1.w + s2.w + s3.w;
    *(f4*)(partial + ((size_t)b * NCH + c) * D_MODEL + d) = s4;
}

// wv[b][d] = sum over 28 chunk partials
__global__ __launch_bounds__(256) void combine(
    const float* __restrict__ partial, float* __restrict__ wv)
{
    const int i = blockIdx.x * 256 + threadIdx.x;   // < 65536
    const int b = i >> 10;
    const int d = i & (D_MODEL - 1);
    float s = 0.f;
#pragma unroll
    for (int c = 0; c < NCH; ++c)
        s += partial[((size_t)b * NCH + c) * D_MODEL + d];
    wv[i] = s;
}

// ---------------------------------------------------------------------------
extern "C" void kernel_launch(void* const* d_in, const int* in_sizes, int n_in,
                              void* d_out, int out_size, void* d_ws, size_t ws_size,
                              hipStream_t stream) {
    const float* x      = (const float*)d_in[0];
    const float* kcache = (const float*)d_in[1];
    const float* vcache = (const float*)d_in[2];
    const int*   idxp   = (const int*)d_in[3];
    const float* amask  = (const float*)d_in[4];
    const float* Wq     = (const float*)d_in[5];
    const float* bq     = (const float*)d_in[6];
    const float* Wk     = (const float*)d_in[7];
    const float* Wv     = (const float*)d_in[8];
    const float* bv     = (const float*)d_in[9];
    const float* Wo     = (const float*)d_in[10];
    const float* bo     = (const float*)d_in[11];

    float* out  = (float*)d_out;                 // [64][1024]
    float* kout = out + 65536;                   // [64][448][1024]
    float* vout = kout + (size_t)B_SZ * S_LEN * D_MODEL;

    float* ws    = (float*)d_ws;
    float* partU = ws + PARTU_OFF;   // gemm partials, later vstream partials
    float* qbuf  = ws + QBUF_OFF;
    float* knbuf = ws + KNBUF_OFF;
    float* vnbuf = ws + VNBUF_OFF;
    float* score = ws + SCORE_OFF;   // raw scores, then softmax in-place
    float* wvws  = ws + WV_OFF;

    // q/k/v projections (k-split partials)
    gemm_part<<<dim3(16, 8, 3), 256, 0, stream>>>(x, Wq, Wk, Wv, partU);

    // q(+bq) / knew / vnew  (qbuf,knbuf,vnbuf are contiguous)
    prep<<<768, 256, 0, stream>>>(partU, bq, bv, qbuf);

    // K copy + raw scores
    kstream<<<B_SZ * NCH, 256, 0, stream>>>(
        kcache, qbuf, knbuf, amask, idxp, kout, score);

    // softmax in place
    softmax_k<<<256, 256, 0, stream>>>(score);

    // V copy + weighted partials (overwrites partU — dead after prep)
    vstream<<<B_SZ * NCH, 256, 0, stream>>>(
        vcache, vnbuf, score, idxp, vout, partU);

    // sum chunk partials -> wv
    combine<<<256, 256, 0, stream>>>(partU, wvws);

    // output projection (writes partU slots 0-7; partial data dead)
    gemm_part<<<dim3(16, 8, 1), 256, 0, stream>>>(wvws, Wo, Wo, Wo, partU);
    reduce_out<<<256, 256, 0, stream>>>(partU, bo, out);
}